// Round 17
// baseline (13920.740 us; speedup 1.0000x reference)
//
#include <hip/hip_runtime.h>
#include <stdint.h>

#pragma clang fp contract(off)

// ---------------------------------------------------------------------------
// ASRNN_general f32-exact WAVE-PER-SAMPLE (zero barriers).
// R16 regressed (cross-step pipelining lengthened the critical path); R15's
// limiter = 5 block-wide barriers x 8 waves + bulk-synchronous idling.
// New decomposition: 1 wave (64 lanes) = 1 sample; lane owns 8 neurons
// (h = l*8+j). Spike exchange via wave-internal LDS byte write + uint64 word
// reads (single-wave workgroup => __syncthreads() degenerates to lgkmcnt).
// Gathers scan uniform 512-bit masks ascending (bit-exact ascending-k chains
// per neuron, validated R11-R16, absmax 1.46e-3) with float4x2 coalesced
// loads and 8 accumulator chains per lane.
// ---------------------------------------------------------------------------

static constexpr int    TS      = 784;
static constexpr size_t WS_WT1  = 0;                    // wh1^T [512][512] f32
static constexpr size_t WS_WT2A = 1u << 20;             // wi2^T
static constexpr size_t WS_WT2B = 2u << 20;             // wh2^T
static constexpr size_t WS_WT3  = 3u << 20;             // wi3^T
static constexpr size_t WS_MP   = 4u << 20;             // u8 [3][784][64] packed masks
static constexpr size_t WS_FRP  = WS_MP + 3u * 784 * 64;// f64 [256][3]

// ---- bit-exact replica of Eigen/cephes float32 exp (validated R11) --------
__device__ __forceinline__ float exp_np(float x) {
  float q = rintf(x * 1.442695040f);
  float r = __fmaf_rn(-q, 0.693359375f, x);
  r = __fmaf_rn(-q, -2.12194440e-4f, r);
  float r2 = r * r;
  float p = 1.9875691500e-4f;
  p = __fmaf_rn(p, r, 1.3981999507e-3f);
  p = __fmaf_rn(p, r, 8.3334519073e-3f);
  p = __fmaf_rn(p, r, 4.1665795894e-2f);
  p = __fmaf_rn(p, r, 1.6666665459e-1f);
  p = __fmaf_rn(p, r, 5.0000001201e-1f);
  p = __fmaf_rn(p, r2, r);
  p = p + 1.0f;
  return ldexpf(p, (int)q);
}

// ---- faithful replica of create_general_mask (validated R11) --------------
__device__ __forceinline__ int mask_val(int l, int h, int t) {
  const double cmin = (l == 0) ? 2.0 : ((l == 1) ? 4.0 : 8.0);
  const double cmax = (l == 0) ? 8.0 : ((l == 1) ? 16.0 : 32.0);
  const double smax = (l == 0) ? 4.0 : ((l == 1) ? 8.0 : 16.0);
  const double cD = (cmax - cmin) / 511.0;
  const double dD = (0.8 - 0.2) / 511.0;
  const double sD = smax / 511.0;
  const double hd = (double)h;
  double cycd = (h == 511) ? cmax : __dadd_rn(cmin, __dmul_rn(hd, cD));
  double dcd  = (h == 511) ? 0.8  : __dadd_rn(0.2,  __dmul_rn(hd, dD));
  double psd  = (h == 511) ? smax : __dmul_rn(hd, sD);
  int cyc = __double2int_rn(cycd);
  int on  = __double2int_rn(__dmul_rn(dcd, (double)cyc));
  int ps  = __double2int_rn(psd);
  int eff = (ps >= cyc) ? 0 : ps;
  int pos = (t % cyc) - eff;
  if (pos < 0) pos += cyc;
  return (pos < on) ? 1 : 0;
}

__global__ void setup_masks(char* __restrict__ ws) {
  const int t = blockIdx.x, l = threadIdx.x;   // 784 x 64
  uint8_t* MP = (uint8_t*)(ws + WS_MP);
  for (int layer = 0; layer < 3; ++layer) {
    uint32_t byte = 0;
    for (int j = 0; j < 8; ++j)
      byte |= (uint32_t)mask_val(layer, l * 8 + j, t) << j;
    MP[(size_t)layer * 784 * 64 + t * 64 + l] = (uint8_t)byte;
  }
}

__global__ void transpose_kernel(const float* __restrict__ wh1,
                                 const float* __restrict__ wi2,
                                 const float* __restrict__ wh2,
                                 const float* __restrict__ wi3,
                                 char* __restrict__ ws) {
  const int k = blockIdx.x;   // 512
  const int m = blockIdx.y;   // 4
  const float* W = (m == 0) ? wh1 : (m == 1) ? wi2 : (m == 2) ? wh2 : wi3;
  float* T = (float*)(ws + (size_t)m * (1u << 20));
  for (int j = threadIdx.x; j < 512; j += 256)
    T[(size_t)k * 512 + j] = W[(size_t)j * 512 + k];
}

// Ascending-(w,bit) scan == ascending-k conditional-add chain per neuron j.
// Bit-exact with R11's dot_full for each of the 8 per-lane accumulators.
__device__ __forceinline__ void scan8(const float* __restrict__ base,
                                      const uint64_t* __restrict__ wv,
                                      float* __restrict__ acc) {
#pragma unroll
  for (int w = 0; w < 8; ++w) {
    uint64_t v = wv[w];
    while (v) {
      int b = __builtin_ctzll(v); v &= v - 1;
      const float* p = base + (((size_t)(w * 64 + b)) << 9);
      float4 A = *(const float4*)p;
      float4 Bq = *(const float4*)(p + 4);
      acc[0] = acc[0] + A.x;  acc[1] = acc[1] + A.y;
      acc[2] = acc[2] + A.z;  acc[3] = acc[3] + A.w;
      acc[4] = acc[4] + Bq.x; acc[5] = acc[5] + Bq.y;
      acc[6] = acc[6] + Bq.z; acc[7] = acc[7] + Bq.w;
    }
  }
}

__global__ __launch_bounds__(64) void rnn_wave(
    const float* __restrict__ x,
    const float* __restrict__ wi1, const float* __restrict__ bi1,
    const float* __restrict__ bh1,
    const float* __restrict__ bi2, const float* __restrict__ bh2,
    const float* __restrict__ bi3,
    const float* __restrict__ wo, const float* __restrict__ bo,
    const float* __restrict__ ta1, const float* __restrict__ ta2,
    const float* __restrict__ ta3, const float* __restrict__ tm1,
    const float* __restrict__ tm2, const float* __restrict__ tm3,
    char* __restrict__ ws, float* __restrict__ d_out) {
  const int n = blockIdx.x;    // sample
  const int l = threadIdx.x;   // lane 0..63; owns neurons h = l*8 .. l*8+7
  const float* WT1  = (const float*)(ws + WS_WT1);
  const float* WT2A = (const float*)(ws + WS_WT2A);
  const float* WT2B = (const float*)(ws + WS_WT2B);
  const float* WT3  = (const float*)(ws + WS_WT3);
  const uint8_t* MP1 = (const uint8_t*)(ws + WS_MP);
  const uint8_t* MP2 = MP1 + (size_t)784 * 64;
  const uint8_t* MP3 = MP2 + (size_t)784 * 64;

  __shared__ float xS[784];
  __shared__ float woS[10 * 513];
  __shared__ uint8_t sbuf[3][64];

  for (int i = l; i < 784; i += 64) xS[i] = x[(size_t)n * 784 + i];
  for (int i = l; i < 5120; i += 64) woS[(i >> 9) * 513 + (i & 511)] = wo[i];

  // per-neuron coefficients (8 per lane), cephes exp replica
  float al1[8], om1[8], ro1[8], omr1[8], wi1v[8], bi1v[8], bh1v[8];
  float al2[8], om2[8], ro2[8], omr2[8], bi2v[8], bh2v[8];
  float al3[8], om3[8], ro3[8], omr3[8], bi3v[8];
  float mem1[8], b1[8], c1[8], mem2[8], b2[8], c2[8], mem3[8], b3[8], c3[8];
#pragma unroll
  for (int j = 0; j < 8; ++j) {
    const int h = l * 8 + j;
    al1[j] = exp_np(-1.0f / tm1[h]); om1[j] = 1.0f - al1[j];
    ro1[j] = exp_np(-1.0f / ta1[h]); omr1[j] = 1.0f - ro1[j];
    al2[j] = exp_np(-1.0f / tm2[h]); om2[j] = 1.0f - al2[j];
    ro2[j] = exp_np(-1.0f / ta2[h]); omr2[j] = 1.0f - ro2[j];
    al3[j] = exp_np(-1.0f / tm3[h]); om3[j] = 1.0f - al3[j];
    ro3[j] = exp_np(-1.0f / ta3[h]); omr3[j] = 1.0f - ro3[j];
    wi1v[j] = wi1[h]; bi1v[j] = bi1[h]; bh1v[j] = bh1[h];
    bi2v[j] = bi2[h]; bh2v[j] = bh2[h]; bi3v[j] = bi3[h];
    mem1[j] = 0.0f; b1[j] = 0.01f; c1[j] = 0.0f;
    mem2[j] = 0.0f; b2[j] = 0.01f; c2[j] = 0.0f;
    mem3[j] = 0.0f; b3[j] = 0.01f; c3[j] = 0.0f;
  }
  float bo_v = (l < 10) ? bo[l] : 0.0f;
  float outv = 0.0f;

  uint64_t w1[8], w2[8];            // spike words of layers 1,2 at t-1
#pragma unroll
  for (int w = 0; w < 8; ++w) { w1[w] = 0; w2[w] = 0; }
  uint32_t sb1 = 0, sb2 = 0, sb3 = 0;  // own prev spike bytes

  const float* bs1 = WT1 + (l << 3);
  const float* bsA = WT2A + (l << 3);
  const float* bsB = WT2B + (l << 3);
  const float* bs3 = WT3 + (l << 3);
  __syncthreads();

  for (int t = 0; t < TS; ++t) {
    const uint32_t mb1 = MP1[t * 64 + l];
    const uint32_t mb2 = MP2[t * 64 + l];
    const uint32_t mb3 = MP3[t * 64 + l];
    const float xv = xS[t];

    // ---- layer 1: gather over w1 (spk1[t-1]) from wh1^T ----
    float acc[8] = {0, 0, 0, 0, 0, 0, 0, 0};
    if (mb1) scan8(bs1, w1, acc);
    uint32_t nb1 = 0;
#pragma unroll
    for (int j = 0; j < 8; ++j) {
      const uint32_t mk = (mb1 >> j) & 1u, osp = (sb1 >> j) & 1u;
      float p = xv * wi1v[j];
      p = p + bi1v[j];
      p = p + acc[j];
      p = p + bh1v[j];
      float t1v = ro1[j] * b1[j];
      float bn = osp ? (t1v + omr1[j]) : t1v;
      float Bth = 0.01f + 1.8f * bn;
      float m3v = mem1[j] * al1[j] + om1[j] * p;
      float mn = osp ? (m3v - Bth) : m3v;
      if (!mk) mn = mem1[j];
      uint32_t sn = (mk && (mn - Bth) > 0.0f) ? 1u : 0u;
      mem1[j] = mn; b1[j] = bn; c1[j] += (float)sn;
      nb1 |= sn << j;
    }
    sb1 = nb1;
    sbuf[0][l] = (uint8_t)nb1;
    __syncthreads();
    uint64_t w1n[8];
    {
      const uint64_t* q = (const uint64_t*)sbuf[0];
#pragma unroll
      for (int w = 0; w < 8; ++w) w1n[w] = q[w];
    }

    // ---- layer 2: a1 over w1n (wi2^T), a2 over w2 (wh2^T) ----
    float a1[8] = {0, 0, 0, 0, 0, 0, 0, 0};
    float a2[8] = {0, 0, 0, 0, 0, 0, 0, 0};
    if (mb2) { scan8(bsA, w1n, a1); scan8(bsB, w2, a2); }
    uint32_t nb2 = 0;
#pragma unroll
    for (int j = 0; j < 8; ++j) {
      const uint32_t mk = (mb2 >> j) & 1u, osp = (sb2 >> j) & 1u;
      float p = a1[j] + bi2v[j];
      p = p + a2[j];
      p = p + bh2v[j];
      float t1v = ro2[j] * b2[j];
      float bn = osp ? (t1v + omr2[j]) : t1v;
      float Bth = 0.01f + 1.8f * bn;
      float m3v = mem2[j] * al2[j] + om2[j] * p;
      float mn = osp ? (m3v - Bth) : m3v;
      if (!mk) mn = mem2[j];
      uint32_t sn = (mk && (mn - Bth) > 0.0f) ? 1u : 0u;
      mem2[j] = mn; b2[j] = bn; c2[j] += (float)sn;
      nb2 |= sn << j;
    }
    sb2 = nb2;
    sbuf[1][l] = (uint8_t)nb2;
    __syncthreads();
    uint64_t w2n[8];
    {
      const uint64_t* q = (const uint64_t*)sbuf[1];
#pragma unroll
      for (int w = 0; w < 8; ++w) w2n[w] = q[w];
    }

    // ---- layer 3: gather over w2n (wi3^T) ----
    float a3[8] = {0, 0, 0, 0, 0, 0, 0, 0};
    if (mb3) scan8(bs3, w2n, a3);
    uint32_t nb3 = 0;
#pragma unroll
    for (int j = 0; j < 8; ++j) {
      const uint32_t mk = (mb3 >> j) & 1u, osp = (sb3 >> j) & 1u;
      float p = a3[j] + bi3v[j];
      float t1v = ro3[j] * b3[j];
      float bn = osp ? (t1v + omr3[j]) : t1v;
      float Bth = 0.01f + 1.8f * bn;
      float m3v = mem3[j] * al3[j] + om3[j] * p;
      float mn = osp ? (m3v - Bth) : m3v;
      if (!mk) mn = mem3[j];
      uint32_t sn = (mk && (mn - Bth) > 0.0f) ? 1u : 0u;
      mem3[j] = mn; b3[j] = bn; c3[j] += (float)sn;
      nb3 |= sn << j;
    }
    sb3 = nb3;
    sbuf[2][l] = (uint8_t)nb3;
    __syncthreads();

    // ---- readout: lanes 0..9, ascending-k chain (order-free for output) ---
    if (l < 10) {
      const uint64_t* q = (const uint64_t*)sbuf[2];
      float s = 0.0f;
      const float* wrow = &woS[l * 513];
#pragma unroll
      for (int w = 0; w < 8; ++w) {
        uint64_t v = q[w];
        while (v) { int b = __builtin_ctzll(v); v &= v - 1; s = s + wrow[w * 64 + b]; }
      }
      float vv = outv + s;
      outv = vv + bo_v;
    }
    __syncthreads();   // protect sbuf reuse next iteration (lgkmcnt only)

#pragma unroll
    for (int w = 0; w < 8; ++w) { w1[w] = w1n[w]; w2[w] = w2n[w]; }
  }

  // ---- outputs ----
#pragma unroll
  for (int j = 0; j < 8; ++j) {
    d_out[2560 + (size_t)n * 512 + l * 8 + j]          = c1[j] / 784.0f;
    d_out[2560 + 131072 + (size_t)n * 512 + l * 8 + j] = c2[j] / 784.0f;
    d_out[2560 + 262144 + (size_t)n * 512 + l * 8 + j] = c3[j] / 784.0f;
  }
  if (l < 10) d_out[(size_t)n * 10 + l] = outv / 784.0f;

  // per-sample f64 partials (exact integers -> order-free)
  double s1 = 0.0, s2 = 0.0, s3 = 0.0;
#pragma unroll
  for (int j = 0; j < 8; ++j) { s1 += (double)c1[j]; s2 += (double)c2[j]; s3 += (double)c3[j]; }
#pragma unroll
  for (int d = 32; d > 0; d >>= 1) {
    s1 += __shfl_down(s1, d);
    s2 += __shfl_down(s2, d);
    s3 += __shfl_down(s3, d);
  }
  if (l == 0) {
    double* FRP = (double*)(ws + WS_FRP);
    FRP[n * 3 + 0] = s1; FRP[n * 3 + 1] = s2; FRP[n * 3 + 2] = s3;
  }
}

__global__ void finalize_fr(char* __restrict__ ws, float* __restrict__ d_out) {
  const int l = threadIdx.x;
  if (l >= 3) return;
  const double* FRP = (const double*)(ws + WS_FRP);
  double s = 0.0;
  for (int n = 0; n < 256; ++n) s += FRP[n * 3 + l];
  d_out[395776 + l] = (float)(s / (131072.0 * 784.0));
}

extern "C" void kernel_launch(void* const* d_in, const int* in_sizes, int n_in,
                              void* d_out, int out_size, void* d_ws, size_t ws_size,
                              hipStream_t stream) {
  (void)in_sizes; (void)n_in; (void)out_size; (void)ws_size;
  const float* x   = (const float*)d_in[0];
  const float* wi1 = (const float*)d_in[1];
  const float* bi1 = (const float*)d_in[2];
  const float* wh1 = (const float*)d_in[3];
  const float* bh1 = (const float*)d_in[4];
  const float* wi2 = (const float*)d_in[5];
  const float* bi2 = (const float*)d_in[6];
  const float* wh2 = (const float*)d_in[7];
  const float* bh2 = (const float*)d_in[8];
  const float* wi3 = (const float*)d_in[9];
  const float* bi3 = (const float*)d_in[10];
  const float* wo  = (const float*)d_in[11];
  const float* bo  = (const float*)d_in[12];
  const float* ta1 = (const float*)d_in[13];
  const float* ta2 = (const float*)d_in[14];
  const float* ta3 = (const float*)d_in[15];
  const float* tm1 = (const float*)d_in[16];
  const float* tm2 = (const float*)d_in[17];
  const float* tm3 = (const float*)d_in[18];
  char*  ws  = (char*)d_ws;
  float* out = (float*)d_out;

  hipLaunchKernelGGL(setup_masks, dim3(TS), dim3(64), 0, stream, ws);
  hipLaunchKernelGGL(transpose_kernel, dim3(512, 4), dim3(256), 0, stream,
                     wh1, wi2, wh2, wi3, ws);
  hipLaunchKernelGGL(rnn_wave, dim3(256), dim3(64), 0, stream,
                     x, wi1, bi1, bh1, bi2, bh2, bi3, wo, bo,
                     ta1, ta2, ta3, tm1, tm2, tm3, ws, out);
  hipLaunchKernelGGL(finalize_fr, dim3(1), dim3(64), 0, stream, ws, out);
}

// Round 18
// 4301.401 us; speedup vs baseline: 3.2363x; 3.2363x over previous
//
#include <hip/hip_runtime.h>
#include <stdint.h>

#pragma clang fp contract(off)

// ---------------------------------------------------------------------------
// ASRNN_general f32-exact SAMPLE-PER-BLOCK v5.
// R15 (4.18ms) best; R16 (dual-Y, regressed: bm3 fed bar5); R17 (wave-per-
// sample, regressed: 1 wave/CU). This round = R15 +
//  (1) barrier-free per-thread register readout (out_sum doesn't feed back
//      -> reorder-tolerant): kills bar5 + bm3 + serial readout scan;
//  (2) phase Y = dual{G3(kl2[t]), G1next(kl1[t])} (now off every barrier
//      path), stashed acc1 -> 2 dual gather phases, 4 barriers per step.
// Spike arithmetic bit-exact (validated R11-R17, absmax 1.46e-3): cephes exp,
// ascending-k conditional-add chains, separate-rounding elementwise.
// ---------------------------------------------------------------------------

static constexpr int    TS      = 784;
static constexpr size_t WS_WT1  = 0;                    // wh1^T [512][512] f32
static constexpr size_t WS_WT2A = 1u << 20;             // wi2^T
static constexpr size_t WS_WT2B = 2u << 20;             // wh2^T
static constexpr size_t WS_WT3  = 3u << 20;             // wi3^T
static constexpr size_t WS_M1   = 4u << 20;             // u8 [784][512]
static constexpr size_t WS_M2   = WS_M1 + (size_t)TS * 512;
static constexpr size_t WS_M3   = WS_M2 + (size_t)TS * 512;
static constexpr size_t WS_FRP  = WS_M3 + (size_t)TS * 512;  // f64 [256][3]

// ---- bit-exact replica of Eigen/cephes float32 exp (validated R11) --------
__device__ __forceinline__ float exp_np(float x) {
  float q = rintf(x * 1.442695040f);
  float r = __fmaf_rn(-q, 0.693359375f, x);
  r = __fmaf_rn(-q, -2.12194440e-4f, r);
  float r2 = r * r;
  float p = 1.9875691500e-4f;
  p = __fmaf_rn(p, r, 1.3981999507e-3f);
  p = __fmaf_rn(p, r, 8.3334519073e-3f);
  p = __fmaf_rn(p, r, 4.1665795894e-2f);
  p = __fmaf_rn(p, r, 1.6666665459e-1f);
  p = __fmaf_rn(p, r, 5.0000001201e-1f);
  p = __fmaf_rn(p, r2, r);
  p = p + 1.0f;
  return ldexpf(p, (int)q);
}

// ---- faithful replica of create_general_mask (validated R11) --------------
__device__ __forceinline__ int mask_val(int l, int h, int t) {
  const double cmin = (l == 0) ? 2.0 : ((l == 1) ? 4.0 : 8.0);
  const double cmax = (l == 0) ? 8.0 : ((l == 1) ? 16.0 : 32.0);
  const double smax = (l == 0) ? 4.0 : ((l == 1) ? 8.0 : 16.0);
  const double cD = (cmax - cmin) / 511.0;
  const double dD = (0.8 - 0.2) / 511.0;
  const double sD = smax / 511.0;
  const double hd = (double)h;
  double cycd = (h == 511) ? cmax : __dadd_rn(cmin, __dmul_rn(hd, cD));
  double dcd  = (h == 511) ? 0.8  : __dadd_rn(0.2,  __dmul_rn(hd, dD));
  double psd  = (h == 511) ? smax : __dmul_rn(hd, sD);
  int cyc = __double2int_rn(cycd);
  int on  = __double2int_rn(__dmul_rn(dcd, (double)cyc));
  int ps  = __double2int_rn(psd);
  int eff = (ps >= cyc) ? 0 : ps;
  int pos = (t % cyc) - eff;
  if (pos < 0) pos += cyc;
  return (pos < on) ? 1 : 0;
}

__global__ void setup_masks(char* __restrict__ ws) {
  const int t = blockIdx.x, tid = threadIdx.x;   // 784 x 256
  uint8_t* m1 = (uint8_t*)(ws + WS_M1);
  uint8_t* m2 = (uint8_t*)(ws + WS_M2);
  uint8_t* m3 = (uint8_t*)(ws + WS_M3);
  for (int h = tid; h < 512; h += 256) {
    m1[t * 512 + h] = (uint8_t)mask_val(0, h, t);
    m2[t * 512 + h] = (uint8_t)mask_val(1, h, t);
    m3[t * 512 + h] = (uint8_t)mask_val(2, h, t);
  }
}

__global__ void transpose_kernel(const float* __restrict__ wh1,
                                 const float* __restrict__ wi2,
                                 const float* __restrict__ wh2,
                                 const float* __restrict__ wi3,
                                 char* __restrict__ ws) {
  const int k = blockIdx.x;   // 512
  const int m = blockIdx.y;   // 4
  const float* W = (m == 0) ? wh1 : (m == 1) ? wi2 : (m == 2) ? wh2 : wi3;
  float* T = (float*)(ws + (size_t)m * (1u << 20));
  for (int j = threadIdx.x; j < 512; j += 256)
    T[(size_t)k * 512 + j] = W[(size_t)j * 512 + k];
}

// f32 state update; identical arithmetic to R11-R17 (validated).
__device__ __forceinline__ uint32_t upd32(float hin, uint32_t mk, uint32_t osp,
                                          float al, float om, float r, float omr,
                                          float& memv, float& bv) {
  float t1 = r * bv;
  float bn = osp ? (t1 + omr) : t1;
  float bt = 1.8f * bn;
  float Bth = 0.01f + bt;
  float m1 = memv * al;
  float m2 = om * hin;
  float m3 = m1 + m2;
  float mn = osp ? (m3 - Bth) : m3;
  if (!mk) mn = memv;
  uint32_t sn = (mk && (mn - Bth) > 0.0f) ? 1u : 0u;
  memv = mn; bv = bn;
  return sn;
}

// Rank-based list expansion: O(1) depth, ascending-k by construction.
__device__ __forceinline__ int expand_list(const uint64_t* __restrict__ bm,
                                           uint32_t mysp, int h,
                                           ushort* __restrict__ kl) {
  const int wh = h >> 6, bpos = h & 63;
  int cnt = 0, rank = 0;
#pragma unroll
  for (int w = 0; w < 8; ++w) {
    uint64_t v = bm[w];
    int pc = __builtin_popcountll(v);
    if (w < wh) rank += pc;
    cnt += pc;
  }
  rank += __builtin_popcountll(bm[wh] & ((1ull << bpos) - 1ull));
  if (mysp) kl[rank] = (ushort)h;
  return cnt;
}

// Ascending-k chain from `from`, 16-deep load pipeline (bit-exact order).
__device__ __forceinline__ float gather_from(const float* __restrict__ base,
                                             const ushort* kl, int from, int cnt,
                                             float s) {
  int i = from;
  for (; i + 16 <= cnt; i += 16) {
    float w0  = base[(size_t)kl[i + 0]  << 9];
    float w1  = base[(size_t)kl[i + 1]  << 9];
    float w2  = base[(size_t)kl[i + 2]  << 9];
    float w3  = base[(size_t)kl[i + 3]  << 9];
    float w4  = base[(size_t)kl[i + 4]  << 9];
    float w5  = base[(size_t)kl[i + 5]  << 9];
    float w6  = base[(size_t)kl[i + 6]  << 9];
    float w7  = base[(size_t)kl[i + 7]  << 9];
    float w8  = base[(size_t)kl[i + 8]  << 9];
    float w9  = base[(size_t)kl[i + 9]  << 9];
    float w10 = base[(size_t)kl[i + 10] << 9];
    float w11 = base[(size_t)kl[i + 11] << 9];
    float w12 = base[(size_t)kl[i + 12] << 9];
    float w13 = base[(size_t)kl[i + 13] << 9];
    float w14 = base[(size_t)kl[i + 14] << 9];
    float w15 = base[(size_t)kl[i + 15] << 9];
    s = s + w0;  s = s + w1;  s = s + w2;  s = s + w3;
    s = s + w4;  s = s + w5;  s = s + w6;  s = s + w7;
    s = s + w8;  s = s + w9;  s = s + w10; s = s + w11;
    s = s + w12; s = s + w13; s = s + w14; s = s + w15;
  }
  for (; i + 4 <= cnt; i += 4) {
    float w0 = base[(size_t)kl[i + 0] << 9];
    float w1 = base[(size_t)kl[i + 1] << 9];
    float w2 = base[(size_t)kl[i + 2] << 9];
    float w3 = base[(size_t)kl[i + 3] << 9];
    s = s + w0; s = s + w1; s = s + w2; s = s + w3;
  }
  for (; i < cnt; ++i) s = s + base[(size_t)kl[i] << 9];
  return s;
}

// Dual interleaved ascending-k chains (8+8); each chain keeps its own order.
__device__ __forceinline__ void dual_gather(
    const float* __restrict__ bA, const ushort* __restrict__ klA, int cntA,
    const float* __restrict__ bB, const ushort* __restrict__ klB, int cntB,
    float& outA, float& outB) {
  float a = 0.0f, b = 0.0f;
  int iA = 0, iB = 0;
  while (iA + 8 <= cntA && iB + 8 <= cntB) {
    float wa0 = bA[(size_t)klA[iA + 0] << 9];
    float wa1 = bA[(size_t)klA[iA + 1] << 9];
    float wa2 = bA[(size_t)klA[iA + 2] << 9];
    float wa3 = bA[(size_t)klA[iA + 3] << 9];
    float wa4 = bA[(size_t)klA[iA + 4] << 9];
    float wa5 = bA[(size_t)klA[iA + 5] << 9];
    float wa6 = bA[(size_t)klA[iA + 6] << 9];
    float wa7 = bA[(size_t)klA[iA + 7] << 9];
    float wb0 = bB[(size_t)klB[iB + 0] << 9];
    float wb1 = bB[(size_t)klB[iB + 1] << 9];
    float wb2 = bB[(size_t)klB[iB + 2] << 9];
    float wb3 = bB[(size_t)klB[iB + 3] << 9];
    float wb4 = bB[(size_t)klB[iB + 4] << 9];
    float wb5 = bB[(size_t)klB[iB + 5] << 9];
    float wb6 = bB[(size_t)klB[iB + 6] << 9];
    float wb7 = bB[(size_t)klB[iB + 7] << 9];
    a = a + wa0; a = a + wa1; a = a + wa2; a = a + wa3;
    a = a + wa4; a = a + wa5; a = a + wa6; a = a + wa7;
    b = b + wb0; b = b + wb1; b = b + wb2; b = b + wb3;
    b = b + wb4; b = b + wb5; b = b + wb6; b = b + wb7;
    iA += 8; iB += 8;
  }
  a = gather_from(bA, klA, iA, cntA, a);
  b = gather_from(bB, klB, iB, cntB, b);
  outA = a; outB = b;
}

__global__ __launch_bounds__(512, 1) void rnn_block(
    const float* __restrict__ x,
    const float* __restrict__ wi1, const float* __restrict__ bi1,
    const float* __restrict__ bh1,
    const float* __restrict__ bi2, const float* __restrict__ bh2,
    const float* __restrict__ bi3,
    const float* __restrict__ wo, const float* __restrict__ bo,
    const float* __restrict__ ta1, const float* __restrict__ ta2,
    const float* __restrict__ ta3, const float* __restrict__ tm1,
    const float* __restrict__ tm2, const float* __restrict__ tm3,
    char* __restrict__ ws, float* __restrict__ d_out) {
  const int n = blockIdx.x;    // sample
  const int h = threadIdx.x;   // neuron 0..511
  const float* WT1  = (const float*)(ws + WS_WT1);
  const float* WT2A = (const float*)(ws + WS_WT2A);
  const float* WT2B = (const float*)(ws + WS_WT2B);
  const float* WT3  = (const float*)(ws + WS_WT3);
  const uint8_t* M1 = (const uint8_t*)(ws + WS_M1);
  const uint8_t* M2 = (const uint8_t*)(ws + WS_M2);
  const uint8_t* M3 = (const uint8_t*)(ws + WS_M3);

  __shared__ uint64_t bm1s[8], bm2s[8];
  __shared__ ushort kl1s[512], kl2s[512];
  __shared__ float outpS[512 * 10];
  __shared__ double red[512];

  float al1 = exp_np(-1.0f / tm1[h]), om1 = 1.0f - al1;
  float ro1 = exp_np(-1.0f / ta1[h]), omr1 = 1.0f - ro1;
  float al2 = exp_np(-1.0f / tm2[h]), om2 = 1.0f - al2;
  float ro2 = exp_np(-1.0f / ta2[h]), omr2 = 1.0f - ro2;
  float al3 = exp_np(-1.0f / tm3[h]), om3 = 1.0f - al3;
  float ro3 = exp_np(-1.0f / ta3[h]), omr3 = 1.0f - ro3;
  float wi1v = wi1[h], bi1v = bi1[h], bh1v = bh1[h];
  float bi2v = bi2[h], bh2v = bh2[h], bi3v = bi3[h];

  // per-thread readout rows: wo[o][h], o = 0..9
  float wov[10], outp[10];
#pragma unroll
  for (int o = 0; o < 10; ++o) { wov[o] = wo[(size_t)o * 512 + h]; outp[o] = 0.0f; }

  float mem1 = 0.0f, b1 = 0.01f, c1 = 0.0f;
  float mem2 = 0.0f, b2 = 0.01f, c2 = 0.0f;
  float mem3 = 0.0f, b3 = 0.01f, c3 = 0.0f;
  uint32_t sp1 = 0, sp2 = 0, sp3 = 0;
  int cnt1 = 0, cnt2 = 0;
  float acc1 = 0.0f;                     // stashed G1 (over kl1[t-1])
  uint32_t mk1 = M1[h];                  // layer-1 mask for current t

  const float* xrow = x + (size_t)n * 784;
  __syncthreads();

  for (int t = 0; t < TS; ++t) {
    const uint32_t mk2 = M2[t * 512 + h];
    const uint32_t mk3 = M3[t * 512 + h];
    const float xv = xrow[t];

    // ---- layer 1 update (acc1 stashed from phase Y of t-1) ----
    float p1 = xv * wi1v;
    p1 = p1 + bi1v;
    p1 = p1 + acc1;
    p1 = p1 + bh1v;
    uint32_t sn1 = upd32(p1, mk1, sp1, al1, om1, ro1, omr1, mem1, b1);
    sp1 = sn1; c1 += (float)sn1;
    uint64_t bal1 = __ballot(sn1);
    if ((h & 63) == 0) bm1s[h >> 6] = bal1;
    __syncthreads();                     // bar1: bm1 visible; kl1s(t-1) reads done
    cnt1 = expand_list(bm1s, sn1, h, kl1s);
    __syncthreads();                     // bar2: kl1s(t) visible

    // ---- phase X: dual gather G2A(kl1[t]) + G2B(kl2[t-1]) ----
    float a1, a2;
    {
      const int cA = mk2 ? cnt1 : 0;
      const int cB = mk2 ? cnt2 : 0;
      dual_gather(WT2A + h, kl1s, cA, WT2B + h, kl2s, cB, a1, a2);
    }
    float p2 = a1 + bi2v;
    p2 = p2 + a2;
    p2 = p2 + bh2v;
    uint32_t sn2 = upd32(p2, mk2, sp2, al2, om2, ro2, omr2, mem2, b2);
    sp2 = sn2; c2 += (float)sn2;
    uint64_t bal2 = __ballot(sn2);
    if ((h & 63) == 0) bm2s[h >> 6] = bal2;
    __syncthreads();                     // bar3: bm2 visible; kl2s(t-1) reads done
    cnt2 = expand_list(bm2s, sn2, h, kl2s);
    __syncthreads();                     // bar4: kl2s(t) visible

    // ---- phase Y: dual gather G3(kl2[t]) + G1next(kl1[t]) ----
    // nothing barriers on layer-3 spikes anymore -> interleave is free.
    const uint32_t mk1n = (t + 1 < TS) ? M1[(t + 1) * 512 + h] : 0u;
    float a3, a1n;
    {
      const int cG3 = mk3 ? cnt2 : 0;
      const int cG1 = mk1n ? cnt1 : 0;
      dual_gather(WT3 + h, kl2s, cG3, WT1 + h, kl1s, cG1, a3, a1n);
    }
    acc1 = a1n;
    mk1 = mk1n;
    float p3 = a3 + bi3v;
    uint32_t sn3 = upd32(p3, mk3, sp3, al3, om3, ro3, omr3, mem3, b3);
    sp3 = sn3; c3 += (float)sn3;

    // ---- barrier-free per-thread readout (out_sum is not fed back) ----
    if (sn3) {
#pragma unroll
      for (int o = 0; o < 10; ++o) outp[o] = outp[o] + wov[o];
    }
  }

  // ---- outputs: rates ----
  d_out[2560 + (size_t)n * 512 + h]          = c1 / 784.0f;
  d_out[2560 + 131072 + (size_t)n * 512 + h] = c2 / 784.0f;
  d_out[2560 + 262144 + (size_t)n * 512 + h] = c3 / 784.0f;

  // ---- out_sum reduction (reorder-tolerant) ----
#pragma unroll
  for (int o = 0; o < 10; ++o) outpS[h * 10 + o] = outp[o];
  __syncthreads();
  if (h < 10) {
    double s = 0.0;
    for (int l = 0; l < 512; ++l) s += (double)outpS[l * 10 + h];
    s += 784.0 * (double)bo[h];
    d_out[(size_t)n * 10 + h] = (float)s / 784.0f;
  }

  // ---- per-block f64 partial sums for layer_fr ----
  double* FRP = (double*)(ws + WS_FRP);
  red[h] = (double)c1;
  __syncthreads();
  for (int wd = 256; wd > 0; wd >>= 1) {
    if (h < wd) red[h] += red[h + wd];
    __syncthreads();
  }
  if (h == 0) FRP[n * 3 + 0] = red[0];
  __syncthreads();
  red[h] = (double)c2;
  __syncthreads();
  for (int wd = 256; wd > 0; wd >>= 1) {
    if (h < wd) red[h] += red[h + wd];
    __syncthreads();
  }
  if (h == 0) FRP[n * 3 + 1] = red[0];
  __syncthreads();
  red[h] = (double)c3;
  __syncthreads();
  for (int wd = 256; wd > 0; wd >>= 1) {
    if (h < wd) red[h] += red[h + wd];
    __syncthreads();
  }
  if (h == 0) FRP[n * 3 + 2] = red[0];
}

__global__ void finalize_fr(char* __restrict__ ws, float* __restrict__ d_out) {
  const int l = threadIdx.x;
  if (l >= 3) return;
  const double* FRP = (const double*)(ws + WS_FRP);
  double s = 0.0;
  for (int n = 0; n < 256; ++n) s += FRP[n * 3 + l];
  d_out[395776 + l] = (float)(s / (131072.0 * 784.0));
}

extern "C" void kernel_launch(void* const* d_in, const int* in_sizes, int n_in,
                              void* d_out, int out_size, void* d_ws, size_t ws_size,
                              hipStream_t stream) {
  (void)in_sizes; (void)n_in; (void)out_size; (void)ws_size;
  const float* x   = (const float*)d_in[0];
  const float* wi1 = (const float*)d_in[1];
  const float* bi1 = (const float*)d_in[2];
  const float* wh1 = (const float*)d_in[3];
  const float* bh1 = (const float*)d_in[4];
  const float* wi2 = (const float*)d_in[5];
  const float* bi2 = (const float*)d_in[6];
  const float* wh2 = (const float*)d_in[7];
  const float* bh2 = (const float*)d_in[8];
  const float* wi3 = (const float*)d_in[9];
  const float* bi3 = (const float*)d_in[10];
  const float* wo  = (const float*)d_in[11];
  const float* bo  = (const float*)d_in[12];
  const float* ta1 = (const float*)d_in[13];
  const float* ta2 = (const float*)d_in[14];
  const float* ta3 = (const float*)d_in[15];
  const float* tm1 = (const float*)d_in[16];
  const float* tm2 = (const float*)d_in[17];
  const float* tm3 = (const float*)d_in[18];
  char*  ws  = (char*)d_ws;
  float* out = (float*)d_out;

  hipLaunchKernelGGL(setup_masks, dim3(TS), dim3(256), 0, stream, ws);
  hipLaunchKernelGGL(transpose_kernel, dim3(512, 4), dim3(256), 0, stream,
                     wh1, wi2, wh2, wi3, ws);
  hipLaunchKernelGGL(rnn_block, dim3(256), dim3(512), 0, stream,
                     x, wi1, bi1, bh1, bi2, bh2, bi3, wo, bo,
                     ta1, ta2, ta3, tm1, tm2, tm3, ws, out);
  hipLaunchKernelGGL(finalize_fr, dim3(1), dim3(64), 0, stream, ws, out);
}